// Round 1
// baseline (149.513 us; speedup 1.0000x reference)
//
#include <hip/hip_runtime.h>

// Problem: B=8, T=2048, C=1024, H=64 single-head causal attention.
// Inputs (f32): x[8,2048,1024], Wk[64,1024], Wq[64,1024], Wv[64,1024]
// Output (f32): out[8,2048,64]
// Strategy: bf16 MFMA (threshold is bf16-grade, 6.2e-2).
//   K1: qkv projection -> bf16 q,k (row-major [B*T,64]) and vT ([B][64][T]) in d_ws
//   K2: flash attention, 1 block per (batch, 64-row q tile), 4 waves.

typedef __attribute__((ext_vector_type(4))) short sv4;
typedef __attribute__((ext_vector_type(8))) short sv8;
typedef __attribute__((ext_vector_type(4))) float f32x4;

#define NB   8
#define TSEQ 2048
#define CDIM 1024
#define HD   64
#define MROWS (NB * TSEQ)   // 16384

__device__ __forceinline__ short f2s(float f) {
  // f32 -> bf16 bits, round-to-nearest-even (finite values only)
  union { float f; unsigned u; } v; v.f = f;
  unsigned u = v.u;
  u += 0x7fffu + ((u >> 16) & 1u);
  return (short)(u >> 16);
}

// ---------------- Kernel 1: QKV projection ----------------
// grid 256 blocks (64 rows each), 256 threads (4 waves).
// Each wave computes 16 rows x 64 cols for q, k, v simultaneously.
__global__ __launch_bounds__(256) void qkv_proj(
    const float* __restrict__ x,
    const float* __restrict__ Wk,
    const float* __restrict__ Wq,
    const float* __restrict__ Wv,
    short* __restrict__ qw,   // [MROWS][64] bf16
    short* __restrict__ kw,   // [MROWS][64] bf16
    short* __restrict__ vtw)  // [NB][64][TSEQ] bf16 (transposed v)
{
  __shared__ short xs[64][128];      // 16 KB
  __shared__ short ws[3][64][128];   // 48 KB
  const int tid  = threadIdx.x;
  const int wid  = tid >> 6;
  const int lane = tid & 63;
  const int g    = lane >> 4;        // 16-lane group 0..3
  const int c16  = lane & 15;
  const int row0 = blockIdx.x * 64;

  const float* Wp[3] = {Wq, Wk, Wv}; // j=0:q, 1:k, 2:v

  f32x4 acc[3][4];
  #pragma unroll
  for (int j = 0; j < 3; ++j)
    #pragma unroll
    for (int n = 0; n < 4; ++n)
      acc[j][n] = (f32x4){0.f, 0.f, 0.f, 0.f};

  for (int k0 = 0; k0 < CDIM; k0 += 128) {
    // stage x tile [64][128] f32 -> bf16
    #pragma unroll
    for (int c = tid; c < 2048; c += 256) {
      int r = c >> 5, c4 = (c & 31) << 2;
      const float4 f = *(const float4*)(x + (size_t)(row0 + r) * CDIM + k0 + c4);
      *(sv4*)&xs[r][c4] = (sv4){f2s(f.x), f2s(f.y), f2s(f.z), f2s(f.w)};
    }
    // stage weight tiles [64][128] f32 -> bf16 (x3)
    #pragma unroll
    for (int j = 0; j < 3; ++j) {
      #pragma unroll
      for (int c = tid; c < 2048; c += 256) {
        int r = c >> 5, c4 = (c & 31) << 2;
        const float4 f = *(const float4*)(Wp[j] + (size_t)r * CDIM + k0 + c4);
        *(sv4*)&ws[j][r][c4] = (sv4){f2s(f.x), f2s(f.y), f2s(f.z), f2s(f.w)};
      }
    }
    __syncthreads();

    #pragma unroll
    for (int kk = 0; kk < 128; kk += 32) {
      sv8 a = *(const sv8*)&xs[(wid << 4) + c16][kk + (g << 3)];
      #pragma unroll
      for (int j = 0; j < 3; ++j) {
        #pragma unroll
        for (int n = 0; n < 4; ++n) {
          sv8 b = *(const sv8*)&ws[j][(n << 4) + c16][kk + (g << 3)];
          acc[j][n] = __builtin_amdgcn_mfma_f32_16x16x32_bf16(a, b, acc[j][n], 0, 0, 0);
        }
      }
    }
    __syncthreads();
  }

  // epilogue: D layout row=(lane>>4)*4+r, col=lane&15  (m89-verified)
  const int orow = row0 + (wid << 4) + (g << 2);
  #pragma unroll
  for (int n = 0; n < 4; ++n) {
    #pragma unroll
    for (int r = 0; r < 4; ++r) {
      int rr = orow + r;
      int cc = (n << 4) + c16;
      qw[(size_t)rr * HD + cc] = f2s(acc[0][n][r]);
      kw[(size_t)rr * HD + cc] = f2s(acc[1][n][r]);
      int b = rr >> 11, t = rr & (TSEQ - 1);
      vtw[((size_t)b * HD + cc) * TSEQ + t] = f2s(acc[2][n][r]);
    }
  }
}

// ---------------- Kernel 2: flash attention ----------------
// grid = NB * (TSEQ/64) = 256 blocks, 256 threads (4 waves).
// Wave w owns q rows [q0 + 16w, q0 + 16w + 16).
__global__ __launch_bounds__(256) void attn(
    const short* __restrict__ qw,
    const short* __restrict__ kw,
    const short* __restrict__ vtw,
    float* __restrict__ out)
{
  __shared__ short ks[64][64];        // K tile, row = key, col = head dim
  __shared__ short vt[64][64];        // V^T tile, row = head dim (out col), col = key
  __shared__ short ps[4][16][64];     // per-wave P buffer (D-layout -> A-layout bridge)

  const int tid  = threadIdx.x;
  const int wid  = tid >> 6;
  const int lane = tid & 63;
  const int g    = lane >> 4;
  const int c16  = lane & 15;

  const int b  = blockIdx.x >> 5;
  const int qt = blockIdx.x & 31;
  const int q0 = qt * 64;
  const size_t base = (size_t)b * TSEQ * HD;

  // Q fragments in registers (A-layout: row = lane&15, k = 8*(lane>>4)+j, contiguous 8)
  const int arow = (wid << 4) + c16;
  const int ak   = g << 3;
  sv8 qa[2];
  qa[0] = *(const sv8*)(qw + base + (size_t)(q0 + arow) * HD + ak);
  qa[1] = *(const sv8*)(qw + base + (size_t)(q0 + arow) * HD + 32 + ak);

  float m[4], l[4];
  f32x4 o[4];
  #pragma unroll
  for (int r = 0; r < 4; ++r) { m[r] = -1e30f; l[r] = 0.f; }
  #pragma unroll
  for (int n = 0; n < 4; ++n) o[n] = (f32x4){0.f, 0.f, 0.f, 0.f};

  const int nkt = qt + 1;
  for (int kt = 0; kt < nkt; ++kt) {
    // ---- stage K tile (linear copy) and V^T tile ----
    {
      const short* kp = kw + base + (size_t)kt * 64 * HD;
      int c = tid;
      #pragma unroll
      for (int it = 0; it < 2; ++it, c += 256)
        *(sv8*)((short*)ks + c * 8) = *(const sv8*)(kp + c * 8);

      const short* vp = vtw + (size_t)b * HD * TSEQ + kt * 64;
      int c2 = tid;
      #pragma unroll
      for (int it = 0; it < 2; ++it, c2 += 256) {
        int h = c2 >> 3, ko = (c2 & 7) << 3;
        *(sv8*)&vt[h][ko] = *(const sv8*)(vp + (size_t)h * TSEQ + ko);
      }
    }
    __syncthreads();

    // ---- S = Q K^T (16x64 per wave) ----
    f32x4 s[4];
    #pragma unroll
    for (int n = 0; n < 4; ++n) s[n] = (f32x4){0.f, 0.f, 0.f, 0.f};
    #pragma unroll
    for (int n = 0; n < 4; ++n) {
      sv8 b0 = *(const sv8*)&ks[(n << 4) + c16][ak];
      s[n] = __builtin_amdgcn_mfma_f32_16x16x32_bf16(qa[0], b0, s[n], 0, 0, 0);
      sv8 b1 = *(const sv8*)&ks[(n << 4) + c16][32 + ak];
      s[n] = __builtin_amdgcn_mfma_f32_16x16x32_bf16(qa[1], b1, s[n], 0, 0, 0);
    }

    // ---- scale + causal mask ----
    const int qrow_base = q0 + (wid << 4) + (g << 2);
    #pragma unroll
    for (int n = 0; n < 4; ++n) {
      int kcol = kt * 64 + (n << 4) + c16;
      #pragma unroll
      for (int r = 0; r < 4; ++r) {
        float val = s[n][r] * 0.03125f;  // C^-0.5 = 1/32
        s[n][r] = (kcol <= qrow_base + r) ? val : -1e30f;
      }
    }

    // ---- online softmax (rows live across the 16-lane group) ----
    #pragma unroll
    for (int r = 0; r < 4; ++r) {
      float mx = fmaxf(fmaxf(s[0][r], s[1][r]), fmaxf(s[2][r], s[3][r]));
      #pragma unroll
      for (int msk = 1; msk < 16; msk <<= 1)
        mx = fmaxf(mx, __shfl_xor(mx, msk));
      float mnew  = fmaxf(m[r], mx);
      float alpha = __expf(m[r] - mnew);
      float sum = 0.f;
      #pragma unroll
      for (int n = 0; n < 4; ++n) {
        float p = __expf(s[n][r] - mnew);
        s[n][r] = p;
        sum += p;
      }
      #pragma unroll
      for (int msk = 1; msk < 16; msk <<= 1)
        sum += __shfl_xor(sum, msk);
      l[r] = l[r] * alpha + sum;
      m[r] = mnew;
      #pragma unroll
      for (int n = 0; n < 4; ++n) {
        o[n][r] *= alpha;
        ps[wid][(g << 2) + r][(n << 4) + c16] = f2s(s[n][r]);
      }
    }

    // same-wave LDS RAW fence (ps write -> ps read)
    asm volatile("s_waitcnt lgkmcnt(0)" ::: "memory");

    // ---- O += P V ----
    #pragma unroll
    for (int kk2 = 0; kk2 < 2; ++kk2) {
      sv8 pa = *(const sv8*)&ps[wid][c16][(kk2 << 5) + ak];
      #pragma unroll
      for (int n = 0; n < 4; ++n) {
        sv8 vb = *(const sv8*)&vt[(n << 4) + c16][(kk2 << 5) + ak];
        o[n] = __builtin_amdgcn_mfma_f32_16x16x32_bf16(pa, vb, o[n], 0, 0, 0);
      }
    }
    __syncthreads();  // protect ks/vt before next tile's staging
  }

  // ---- epilogue: O / l ----
  const int qrow_base = q0 + (wid << 4) + (g << 2);
  #pragma unroll
  for (int n = 0; n < 4; ++n) {
    #pragma unroll
    for (int r = 0; r < 4; ++r) {
      out[base + (size_t)(qrow_base + r) * HD + (n << 4) + c16] = o[n][r] / l[r];
    }
  }
}

extern "C" void kernel_launch(void* const* d_in, const int* in_sizes, int n_in,
                              void* d_out, int out_size, void* d_ws, size_t ws_size,
                              hipStream_t stream) {
  const float* x  = (const float*)d_in[0];
  const float* Wk = (const float*)d_in[1];
  const float* Wq = (const float*)d_in[2];
  const float* Wv = (const float*)d_in[3];
  float* out = (float*)d_out;

  short* qw  = (short*)d_ws;                       // 2 MB
  short* kw  = qw + (size_t)MROWS * HD;            // 2 MB
  short* vtw = kw + (size_t)MROWS * HD;            // 2 MB

  qkv_proj<<<dim3(MROWS / 64), dim3(256), 0, stream>>>(x, Wk, Wq, Wv, qw, kw, vtw);
  attn<<<dim3(NB * (TSEQ / 64)), dim3(256), 0, stream>>>(qw, kw, vtw, out);
}

// Round 2
// 100.868 us; speedup vs baseline: 1.4823x; 1.4823x over previous
//
#include <hip/hip_runtime.h>

// B=8, T=2048, C=1024, H=64 single-head causal attention, f32 in/out.
// Round 2: kill 16-way LDS bank conflicts (XOR swizzle on 16B slots),
// preconvert weights to bf16 once, register-prefetch double buffering.

typedef __attribute__((ext_vector_type(8))) short sv8;
typedef __attribute__((ext_vector_type(4))) float f32x4;

#define NB   8
#define TSEQ 2048
#define CDIM 1024
#define HD   64
#define MROWS (NB * TSEQ)   // 16384

__device__ __forceinline__ short f2s(float f) {
  union { float f; unsigned u; } v; v.f = f;
  unsigned u = v.u;
  u += 0x7fffu + ((u >> 16) & 1u);
  return (short)(u >> 16);
}
// swizzle: 16B-slot xor'd with row bits (T2). sw16 for 256B rows (16 slots),
// sw8 for 128B rows (8 slots).
__device__ __forceinline__ int sw16(int row, int slot) { return slot ^ (row & 15); }
__device__ __forceinline__ int sw8 (int row, int slot) { return slot ^ (row & 7); }

// ---------------- Kernel 0: weights f32 -> bf16, once ----------------
__global__ __launch_bounds__(256) void wcvt(
    const float* __restrict__ Wq, const float* __restrict__ Wk,
    const float* __restrict__ Wv, short* __restrict__ wb)  // wb[3][64][1024]
{
  int i = blockIdx.x * 256 + threadIdx.x;   // 24576 threads, 8 elems each
  const float* src = (i < 8192) ? Wq : (i < 16384) ? Wk : Wv;
  int rem = i & 8191;
  const float4 a = *(const float4*)(src + rem * 8);
  const float4 b = *(const float4*)(src + rem * 8 + 4);
  sv8 v = {f2s(a.x), f2s(a.y), f2s(a.z), f2s(a.w),
           f2s(b.x), f2s(b.y), f2s(b.z), f2s(b.w)};
  *(sv8*)(wb + (size_t)i * 8) = v;
}

// ---------------- Kernel 1: QKV projection ----------------
// 256 blocks x 256 threads (4 waves). Block = 64 rows, all 192 output cols.
__global__ __launch_bounds__(256) void qkv_proj(
    const float* __restrict__ x,
    const short* __restrict__ wb,   // [3][64][1024] bf16, j: 0=q,1=k,2=v
    short* __restrict__ qw,         // [MROWS][64] bf16
    short* __restrict__ kw,         // [MROWS][64] bf16
    short* __restrict__ vtw)        // [NB][64][TSEQ] bf16
{
  __shared__ short xs[64 * 128];       // 16 KB, swizzled
  __shared__ short ws[3 * 64 * 128];   // 48 KB, swizzled
  const int tid  = threadIdx.x;
  const int wid  = tid >> 6;
  const int lane = tid & 63;
  const int g    = lane >> 4;
  const int c16  = lane & 15;
  const int row0 = blockIdx.x * 64;

  f32x4 acc[3][4];
  #pragma unroll
  for (int j = 0; j < 3; ++j)
    #pragma unroll
    for (int n = 0; n < 4; ++n)
      acc[j][n] = (f32x4){0.f, 0.f, 0.f, 0.f};

  float4 px[8];   // x prefetch: 4 chunks x 2 float4
  sv8    pw[12];  // W prefetch: 12 chunks

  #define QLOAD(k0)                                                          \
    {                                                                        \
      _Pragma("unroll")                                                      \
      for (int it = 0; it < 4; ++it) {                                       \
        int c = tid + it * 256, r = c >> 4, s = c & 15;                      \
        const float* p = x + (size_t)(row0 + r) * CDIM + (k0) + s * 8;       \
        px[it * 2]     = *(const float4*)p;                                  \
        px[it * 2 + 1] = *(const float4*)(p + 4);                            \
      }                                                                      \
      _Pragma("unroll")                                                      \
      for (int it = 0; it < 12; ++it) {                                      \
        int c = tid + it * 256, j = c >> 10, rem = c & 1023;                 \
        int r = rem >> 4, s = rem & 15;                                      \
        pw[it] = *(const sv8*)(wb + ((size_t)j * 64 + r) * CDIM + (k0) + s * 8); \
      }                                                                      \
    }
  #define QSTORE()                                                           \
    {                                                                        \
      _Pragma("unroll")                                                      \
      for (int it = 0; it < 4; ++it) {                                       \
        int c = tid + it * 256, r = c >> 4, s = c & 15;                      \
        float4 A = px[it * 2], Bv = px[it * 2 + 1];                          \
        sv8 v = {f2s(A.x), f2s(A.y), f2s(A.z), f2s(A.w),                     \
                 f2s(Bv.x), f2s(Bv.y), f2s(Bv.z), f2s(Bv.w)};                \
        *(sv8*)&xs[r * 128 + (sw16(r, s) << 3)] = v;                         \
      }                                                                      \
      _Pragma("unroll")                                                      \
      for (int it = 0; it < 12; ++it) {                                      \
        int c = tid + it * 256, j = c >> 10, rem = c & 1023;                 \
        int r = rem >> 4, s = rem & 15;                                      \
        *(sv8*)&ws[j * 8192 + r * 128 + (sw16(r, s) << 3)] = pw[it];         \
      }                                                                      \
    }

  QLOAD(0);
  QSTORE();
  __syncthreads();

  const int arow = (wid << 4) + c16;
  for (int t = 0; t < 8; ++t) {
    if (t < 7) QLOAD((t + 1) * 128);

    #pragma unroll
    for (int kk = 0; kk < 128; kk += 32) {
      sv8 a0 = *(const sv8*)&xs[arow * 128 + (sw16(arow, (kk >> 3) + g) << 3)];
      #pragma unroll
      for (int j = 0; j < 3; ++j) {
        #pragma unroll
        for (int n = 0; n < 4; ++n) {
          int brow = (n << 4) + c16;
          sv8 b = *(const sv8*)&ws[j * 8192 + brow * 128 +
                                   (sw16(brow, (kk >> 3) + g) << 3)];
          acc[j][n] = __builtin_amdgcn_mfma_f32_16x16x32_bf16(a0, b, acc[j][n], 0, 0, 0);
        }
      }
    }
    __syncthreads();
    if (t < 7) { QSTORE(); }
    __syncthreads();
  }

  // epilogue: D layout row=(lane>>4)*4+r, col=lane&15
  const int orow = row0 + (wid << 4) + (g << 2);
  #pragma unroll
  for (int n = 0; n < 4; ++n) {
    #pragma unroll
    for (int r = 0; r < 4; ++r) {
      int rr = orow + r;
      int cc = (n << 4) + c16;
      qw[(size_t)rr * HD + cc] = f2s(acc[0][n][r]);
      kw[(size_t)rr * HD + cc] = f2s(acc[1][n][r]);
      int b = rr >> 11, tt = rr & (TSEQ - 1);
      vtw[((size_t)b * HD + cc) * TSEQ + tt] = f2s(acc[2][n][r]);
    }
  }
}

// ---------------- Kernel 2: flash attention ----------------
// 256 blocks x 256 threads (4 waves). Wave w owns q rows [q0+16w, q0+16w+16).
__global__ __launch_bounds__(256) void attn(
    const short* __restrict__ qw,
    const short* __restrict__ kw,
    const short* __restrict__ vtw,
    float* __restrict__ out)
{
  __shared__ short ks[64 * 64];       // K tile: row=key, col=dim (swizzled)
  __shared__ short vt[64 * 64];       // V^T tile: row=dim, col=key (swizzled)
  __shared__ short ps[4 * 16 * 64];   // per-wave P bridge (swizzled)

  const int tid  = threadIdx.x;
  const int wid  = tid >> 6;
  const int lane = tid & 63;
  const int g    = lane >> 4;
  const int c16  = lane & 15;

  const int b  = blockIdx.x >> 5;
  const int qt = blockIdx.x & 31;
  const int q0 = qt * 64;
  const size_t base = (size_t)b * TSEQ * HD;

  const int arow = (wid << 4) + c16;
  const int ak   = g << 3;
  sv8 qa[2];
  qa[0] = *(const sv8*)(qw + base + (size_t)(q0 + arow) * HD + ak);
  qa[1] = *(const sv8*)(qw + base + (size_t)(q0 + arow) * HD + 32 + ak);

  float m[4], l[4];
  f32x4 o[4];
  #pragma unroll
  for (int r = 0; r < 4; ++r) { m[r] = -1e30f; l[r] = 0.f; }
  #pragma unroll
  for (int n = 0; n < 4; ++n) o[n] = (f32x4){0.f, 0.f, 0.f, 0.f};

  sv8 pk[2], pv[2];
  #define ALOAD(kt)                                                          \
    {                                                                        \
      const short* kp = kw + base + (size_t)(kt) * 64 * HD;                  \
      _Pragma("unroll")                                                      \
      for (int it = 0; it < 2; ++it) {                                       \
        int c = tid + it * 256;                                              \
        pk[it] = *(const sv8*)(kp + c * 8);                                  \
      }                                                                      \
      const short* vp = vtw + (size_t)b * HD * TSEQ + (kt) * 64;             \
      _Pragma("unroll")                                                      \
      for (int it = 0; it < 2; ++it) {                                       \
        int c = tid + it * 256, h = c >> 3, ko = (c & 7) << 3;               \
        pv[it] = *(const sv8*)(vp + (size_t)h * TSEQ + ko);                  \
      }                                                                      \
    }
  #define ASTORE()                                                           \
    {                                                                        \
      _Pragma("unroll")                                                      \
      for (int it = 0; it < 2; ++it) {                                       \
        int c = tid + it * 256, r = c >> 3, s = c & 7;                       \
        *(sv8*)&ks[r * 64 + (sw8(r, s) << 3)] = pk[it];                      \
      }                                                                      \
      _Pragma("unroll")                                                      \
      for (int it = 0; it < 2; ++it) {                                       \
        int c = tid + it * 256, r = c >> 3, s = c & 7;                       \
        *(sv8*)&vt[r * 64 + (sw8(r, s) << 3)] = pv[it];                      \
      }                                                                      \
    }

  ALOAD(0);
  ASTORE();
  __syncthreads();

  const int nkt = qt + 1;
  const int qrow_base = q0 + (wid << 4) + (g << 2);
  for (int kt = 0; kt < nkt; ++kt) {
    if (kt + 1 < nkt) ALOAD(kt + 1);

    // ---- S = Q K^T ----
    f32x4 s[4];
    #pragma unroll
    for (int n = 0; n < 4; ++n) s[n] = (f32x4){0.f, 0.f, 0.f, 0.f};
    #pragma unroll
    for (int n = 0; n < 4; ++n) {
      int brow = (n << 4) + c16;
      sv8 b0 = *(const sv8*)&ks[brow * 64 + (sw8(brow, g) << 3)];
      s[n] = __builtin_amdgcn_mfma_f32_16x16x32_bf16(qa[0], b0, s[n], 0, 0, 0);
      sv8 b1 = *(const sv8*)&ks[brow * 64 + (sw8(brow, 4 + g) << 3)];
      s[n] = __builtin_amdgcn_mfma_f32_16x16x32_bf16(qa[1], b1, s[n], 0, 0, 0);
    }

    // ---- scale + causal mask ----
    #pragma unroll
    for (int n = 0; n < 4; ++n) {
      int kcol = kt * 64 + (n << 4) + c16;
      #pragma unroll
      for (int r = 0; r < 4; ++r) {
        float val = s[n][r] * 0.03125f;  // C^-0.5 = 1/32
        s[n][r] = (kcol <= qrow_base + r) ? val : -1e30f;
      }
    }

    // ---- online softmax (rows across 16-lane group) ----
    #pragma unroll
    for (int r = 0; r < 4; ++r) {
      float mx = fmaxf(fmaxf(s[0][r], s[1][r]), fmaxf(s[2][r], s[3][r]));
      #pragma unroll
      for (int msk = 1; msk < 16; msk <<= 1)
        mx = fmaxf(mx, __shfl_xor(mx, msk));
      float mnew  = fmaxf(m[r], mx);
      float alpha = __expf(m[r] - mnew);
      float sum = 0.f;
      #pragma unroll
      for (int n = 0; n < 4; ++n) {
        float p = __expf(s[n][r] - mnew);
        s[n][r] = p;
        sum += p;
      }
      #pragma unroll
      for (int msk = 1; msk < 16; msk <<= 1)
        sum += __shfl_xor(sum, msk);
      l[r] = l[r] * alpha + sum;
      m[r] = mnew;
      int prow = (g << 2) + r;
      #pragma unroll
      for (int n = 0; n < 4; ++n) {
        o[n][r] *= alpha;
        int col = (n << 4) + c16;
        ps[wid * 1024 + prow * 64 + (sw8(prow, col >> 3) << 3) + (col & 7)] =
            f2s(s[n][r]);
      }
    }

    // same-wave LDS RAW fence (ps write -> ps read)
    asm volatile("s_waitcnt lgkmcnt(0)" ::: "memory");
    __builtin_amdgcn_sched_barrier(0);

    // ---- O += P V ----
    #pragma unroll
    for (int kk2 = 0; kk2 < 2; ++kk2) {
      sv8 pa = *(const sv8*)&ps[wid * 1024 + c16 * 64 +
                                (sw8(c16, (kk2 << 2) + g) << 3)];
      #pragma unroll
      for (int n = 0; n < 4; ++n) {
        int vrow = (n << 4) + c16;
        sv8 vb = *(const sv8*)&vt[vrow * 64 + (sw8(vrow, (kk2 << 2) + g) << 3)];
        o[n] = __builtin_amdgcn_mfma_f32_16x16x32_bf16(pa, vb, o[n], 0, 0, 0);
      }
    }
    __syncthreads();             // everyone done reading ks/vt
    if (kt + 1 < nkt) { ASTORE(); }
    __syncthreads();             // next tile visible
  }

  // ---- epilogue ----
  #pragma unroll
  for (int n = 0; n < 4; ++n) {
    #pragma unroll
    for (int r = 0; r < 4; ++r) {
      out[base + (size_t)(qrow_base + r) * HD + (n << 4) + c16] = o[n][r] / l[r];
    }
  }
}

extern "C" void kernel_launch(void* const* d_in, const int* in_sizes, int n_in,
                              void* d_out, int out_size, void* d_ws, size_t ws_size,
                              hipStream_t stream) {
  const float* x  = (const float*)d_in[0];
  const float* Wk = (const float*)d_in[1];
  const float* Wq = (const float*)d_in[2];
  const float* Wv = (const float*)d_in[3];
  float* out = (float*)d_out;

  short* qw  = (short*)d_ws;                        // 2 MB
  short* kw  = qw + (size_t)MROWS * HD;             // 2 MB
  short* vtw = kw + (size_t)MROWS * HD;             // 2 MB
  short* wb  = vtw + (size_t)NB * HD * TSEQ;        // 384 KB

  wcvt<<<dim3(96), dim3(256), 0, stream>>>(Wq, Wk, Wv, wb);
  qkv_proj<<<dim3(MROWS / 64), dim3(256), 0, stream>>>(x, wb, qw, kw, vtw);
  attn<<<dim3(NB * (TSEQ / 64)), dim3(256), 0, stream>>>(qw, kw, vtw, out);
}

// Round 3
// 70.155 us; speedup vs baseline: 2.1312x; 1.4378x over previous
//
#include <hip/hip_runtime.h>

// B=8, T=2048, C=1024, H=64 single-head causal attention, f32 in/out.
// Round 3: barrier-free attn (1 wave = 1 q-chunk x K-half, direct global K/V,
// in-block split-K combine), register-direct x in qkv, 512-block grids.

typedef __attribute__((ext_vector_type(8))) short sv8;
typedef __attribute__((ext_vector_type(4))) float f32x4;

#define NB   8
#define TSEQ 2048
#define CDIM 1024
#define HD   64
#define MROWS (NB * TSEQ)   // 16384

__device__ __forceinline__ short f2s(float f) {
  union { float f; unsigned u; } v; v.f = f;
  unsigned u = v.u;
  u += 0x7fffu + ((u >> 16) & 1u);
  return (short)(u >> 16);
}
__device__ __forceinline__ int sw16(int row, int slot) { return slot ^ (row & 15); }

// ---------------- Kernel 0: weights f32 -> bf16, once ----------------
__global__ __launch_bounds__(256) void wcvt(
    const float* __restrict__ Wq, const float* __restrict__ Wk,
    const float* __restrict__ Wv, short* __restrict__ wb)  // wb[3][64][1024]
{
  int i = blockIdx.x * 256 + threadIdx.x;
  const float* src = (i < 8192) ? Wq : (i < 16384) ? Wk : Wv;
  int rem = i & 8191;
  const float4 a = *(const float4*)(src + rem * 8);
  const float4 b = *(const float4*)(src + rem * 8 + 4);
  sv8 v = {f2s(a.x), f2s(a.y), f2s(a.z), f2s(a.w),
           f2s(b.x), f2s(b.y), f2s(b.z), f2s(b.w)};
  *(sv8*)(wb + (size_t)i * 8) = v;
}

// ---------------- Kernel 1: QKV projection ----------------
// 512 blocks x 256 threads (4 waves). Block = 32 x-rows, 192 out cols.
// Wave w: row-group rg=w>>1 (16 rows), (j,n)-pairs p in [6*(w&1), +6).
// x is loaded straight into registers (A-fragments), only W staged in LDS.
__global__ __launch_bounds__(256) void qkv_proj(
    const float* __restrict__ x,
    const short* __restrict__ wb,   // [3][64][1024] bf16
    short* __restrict__ qw,         // [MROWS][64] bf16 (q * 1/32 folded)
    short* __restrict__ kw,         // [MROWS][64] bf16
    short* __restrict__ vtw)        // [NB][64][TSEQ] bf16
{
  __shared__ short ws[3 * 64 * 128];   // 48 KB, swizzled
  const int tid  = threadIdx.x;
  const int wid  = tid >> 6;
  const int lane = tid & 63;
  const int g    = lane >> 4;
  const int c16  = lane & 15;
  const int rg   = wid >> 1;
  const int p0   = (wid & 1) * 6;
  const int row0 = blockIdx.x * 32;
  const int xrow = row0 + (rg << 4) + c16;
  const float* xp = x + (size_t)xrow * CDIM + (g << 3);

  f32x4 acc[6];
  #pragma unroll
  for (int p = 0; p < 6; ++p) acc[p] = (f32x4){0.f, 0.f, 0.f, 0.f};

  float4 px[2][8];
  sv8 pw[12];

  #define WLOAD(k0)                                                           \
    { _Pragma("unroll")                                                       \
      for (int it = 0; it < 12; ++it) {                                       \
        int cc = tid + it * 256, j = cc >> 10, rem = cc & 1023;               \
        int r = rem >> 4, s = rem & 15;                                       \
        pw[it] = *(const sv8*)(wb + ((size_t)j * 64 + r) * CDIM + (k0) + s * 8); \
      } }
  #define WSTORE()                                                            \
    { _Pragma("unroll")                                                       \
      for (int it = 0; it < 12; ++it) {                                       \
        int cc = tid + it * 256, j = cc >> 10, rem = cc & 1023;               \
        int r = rem >> 4, s = rem & 15;                                       \
        *(sv8*)&ws[j * 8192 + r * 128 + (sw16(r, s) << 3)] = pw[it];          \
      } }
  #define XLOAD(buf, k0)                                                      \
    { _Pragma("unroll")                                                       \
      for (int kk = 0; kk < 4; ++kk) {                                        \
        const float* p = xp + (k0) + kk * 32;                                 \
        (buf)[kk * 2]     = *(const float4*)p;                                \
        (buf)[kk * 2 + 1] = *(const float4*)(p + 4);                          \
      } }

  XLOAD(px[0], 0);
  WLOAD(0);
  WSTORE();
  __syncthreads();

  #pragma unroll
  for (int t = 0; t < 8; ++t) {
    if (t < 7) { XLOAD(px[(t + 1) & 1], (t + 1) * 128); WLOAD((t + 1) * 128); }

    #pragma unroll
    for (int kk = 0; kk < 4; ++kk) {
      float4 A = px[t & 1][kk * 2], B = px[t & 1][kk * 2 + 1];
      sv8 a = {f2s(A.x), f2s(A.y), f2s(A.z), f2s(A.w),
               f2s(B.x), f2s(B.y), f2s(B.z), f2s(B.w)};
      #pragma unroll
      for (int p6 = 0; p6 < 6; ++p6) {
        int pp = p0 + p6, j = pp >> 2, n = pp & 3;
        int brow = (n << 4) + c16;
        sv8 bf = *(const sv8*)&ws[j * 8192 + brow * 128 +
                                  (sw16(brow, kk * 4 + g) << 3)];
        acc[p6] = __builtin_amdgcn_mfma_f32_16x16x32_bf16(a, bf, acc[p6], 0, 0, 0);
      }
    }
    if (t < 7) { __syncthreads(); WSTORE(); __syncthreads(); }
  }

  // epilogue: D row = 4g + r, col = 16n + c16
  #pragma unroll
  for (int p6 = 0; p6 < 6; ++p6) {
    int pp = p0 + p6, j = pp >> 2, n = pp & 3;
    #pragma unroll
    for (int r = 0; r < 4; ++r) {
      int rr = row0 + (rg << 4) + (g << 2) + r;
      int cc = (n << 4) + c16;
      if (j == 0) {
        qw[(size_t)rr * HD + cc] = f2s(acc[p6][r] * 0.03125f);  // fold C^-0.5
      } else if (j == 1) {
        kw[(size_t)rr * HD + cc] = f2s(acc[p6][r]);
      } else {
        vtw[((size_t)(rr >> 11) * HD + cc) * TSEQ + (rr & (TSEQ - 1))] =
            f2s(acc[p6][r]);
      }
    }
  }
  #undef WLOAD
  #undef WSTORE
  #undef XLOAD
}

// ---------------- Kernel 2: flash attention, barrier-free ----------------
// 512 blocks x 4 waves. bid: batch = bid&7, i = bid>>3 (0..63).
// Wave wid: chunk = (wid>>1) ? 127-i : i  (16 q rows), half = wid&1 of its
// key range (tiles of 128 keys). K/V read direct from global (L2/L3).
// End: halves merge (m,l,O) via LDS, half-0 writes out.
__global__ __launch_bounds__(256) void attn(
    const short* __restrict__ qw,
    const short* __restrict__ kw,
    const short* __restrict__ vtw,
    float* __restrict__ out)
{
  __shared__ short ps[4][16 * 128];   // per-wave P bridge, swizzled (16 KB)
  __shared__ float cmb[2][16][66];    // split-K exchange (8.25 KB)

  const int tid  = threadIdx.x;
  const int wid  = tid >> 6;
  const int lane = tid & 63;
  const int g    = lane >> 4;
  const int c16  = lane & 15;

  const int batch = blockIdx.x & 7;
  const int i     = blockIdx.x >> 3;
  const int ch    = wid >> 1;
  const int h     = wid & 1;
  const int c     = ch ? (127 - i) : i;
  const int q0    = c << 4;
  const size_t base = (size_t)batch * TSEQ * HD;

  const int n_c = (c + 8) >> 3;        // ceil((c+1)/8) tiles of 128 keys
  const int th  = (n_c + 1) >> 1;
  const int t0  = h ? th : 0;
  const int t1  = h ? n_c : th;

  // Q fragments (A-layout: row=c16, k=8g..8g+7); scale already folded in.
  sv8 qa0 = *(const sv8*)(qw + base + (size_t)(q0 + c16) * HD + (g << 3));
  sv8 qa1 = *(const sv8*)(qw + base + (size_t)(q0 + c16) * HD + 32 + (g << 3));

  float m[4], l[4];
  f32x4 o[4];
  #pragma unroll
  for (int r = 0; r < 4; ++r) { m[r] = -1e30f; l[r] = 0.f; }
  #pragma unroll
  for (int n = 0; n < 4; ++n) o[n] = (f32x4){0.f, 0.f, 0.f, 0.f};

  short* myps = (short*)ps + wid * 2048;

  for (int t = t0; t < t1; ++t) {
    // ---- K fragments direct from global ----
    const short* kb = kw + base + ((size_t)t * 128 + c16) * HD + (g << 3);
    sv8 fr[16];
    #pragma unroll
    for (int n = 0; n < 8; ++n) {
      fr[2 * n]     = *(const sv8*)(kb + n * 16 * HD);
      fr[2 * n + 1] = *(const sv8*)(kb + n * 16 * HD + 32);
    }
    // ---- S = Q K^T (16 x 128) ----
    f32x4 s[8];
    #pragma unroll
    for (int n = 0; n < 8; ++n) s[n] = (f32x4){0.f, 0.f, 0.f, 0.f};
    #pragma unroll
    for (int n = 0; n < 8; ++n) {
      s[n] = __builtin_amdgcn_mfma_f32_16x16x32_bf16(qa0, fr[2 * n], s[n], 0, 0, 0);
      s[n] = __builtin_amdgcn_mfma_f32_16x16x32_bf16(qa1, fr[2 * n + 1], s[n], 0, 0, 0);
    }
    // ---- causal mask (scale folded into q) ----
    const int qrow = q0 + (g << 2);
    #pragma unroll
    for (int n = 0; n < 8; ++n) {
      int kcol = t * 128 + (n << 4) + c16;
      #pragma unroll
      for (int r = 0; r < 4; ++r)
        s[n][r] = (kcol <= qrow + r) ? s[n][r] : -1e30f;
    }
    // ---- V fragments (reuse fr) : B-frag row = d = 16n+c16, k = key ----
    const short* vb = vtw + ((size_t)batch * HD + c16) * TSEQ + t * 128 + (g << 3);
    #pragma unroll
    for (int kk = 0; kk < 4; ++kk)
      #pragma unroll
      for (int n = 0; n < 4; ++n)
        fr[(kk << 2) + n] = *(const sv8*)(vb + (size_t)n * 16 * TSEQ + kk * 32);

    // ---- online softmax (rows across 16-lane group) ----
    #pragma unroll
    for (int r = 0; r < 4; ++r) {
      float mx = fmaxf(fmaxf(fmaxf(s[0][r], s[1][r]), fmaxf(s[2][r], s[3][r])),
                       fmaxf(fmaxf(s[4][r], s[5][r]), fmaxf(s[6][r], s[7][r])));
      #pragma unroll
      for (int msk = 1; msk < 16; msk <<= 1)
        mx = fmaxf(mx, __shfl_xor(mx, msk));
      float mnew  = fmaxf(m[r], mx);
      float alpha = __expf(m[r] - mnew);
      float sum = 0.f;
      #pragma unroll
      for (int n = 0; n < 8; ++n) {
        float p = __expf(s[n][r] - mnew);
        s[n][r] = p;
        sum += p;
      }
      #pragma unroll
      for (int msk = 1; msk < 16; msk <<= 1)
        sum += __shfl_xor(sum, msk);
      l[r] = l[r] * alpha + sum;
      m[r] = mnew;
      #pragma unroll
      for (int n = 0; n < 4; ++n) o[n][r] *= alpha;
      int prow = (g << 2) + r;
      #pragma unroll
      for (int n = 0; n < 8; ++n) {
        int col = (n << 4) + c16;
        myps[prow * 128 + (sw16(prow, col >> 3) << 3) + (col & 7)] = f2s(s[n][r]);
      }
    }
    asm volatile("s_waitcnt lgkmcnt(0)" ::: "memory");
    __builtin_amdgcn_sched_barrier(0);

    // ---- O += P V ----
    #pragma unroll
    for (int kk = 0; kk < 4; ++kk) {
      sv8 pa = *(const sv8*)&myps[c16 * 128 + (sw16(c16, (kk << 2) + g) << 3)];
      #pragma unroll
      for (int n = 0; n < 4; ++n)
        o[n] = __builtin_amdgcn_mfma_f32_16x16x32_bf16(pa, fr[(kk << 2) + n], o[n], 0, 0, 0);
    }
  }

  // ---- split-K combine: half-1 publishes, half-0 merges and writes ----
  if (h == 1) {
    #pragma unroll
    for (int r = 0; r < 4; ++r) {
      int row = (g << 2) + r;
      #pragma unroll
      for (int n = 0; n < 4; ++n)
        cmb[ch][row][(n << 4) + c16] = o[n][r];
      if (c16 == 0) { cmb[ch][row][64] = m[r]; cmb[ch][row][65] = l[r]; }
    }
  }
  __syncthreads();
  if (h == 0) {
    #pragma unroll
    for (int r = 0; r < 4; ++r) {
      int row = (g << 2) + r;
      float m1 = cmb[ch][row][64], l1 = cmb[ch][row][65];
      float M  = fmaxf(m[r], m1);
      float a0 = __expf(m[r] - M), a1 = __expf(m1 - M);
      float invL = 1.f / (l[r] * a0 + l1 * a1);
      #pragma unroll
      for (int n = 0; n < 4; ++n) {
        float v = (o[n][r] * a0 + cmb[ch][row][(n << 4) + c16] * a1) * invL;
        out[base + (size_t)(q0 + row) * HD + (n << 4) + c16] = v;
      }
    }
  }
}

extern "C" void kernel_launch(void* const* d_in, const int* in_sizes, int n_in,
                              void* d_out, int out_size, void* d_ws, size_t ws_size,
                              hipStream_t stream) {
  const float* x  = (const float*)d_in[0];
  const float* Wk = (const float*)d_in[1];
  const float* Wq = (const float*)d_in[2];
  const float* Wv = (const float*)d_in[3];
  float* out = (float*)d_out;

  short* qw  = (short*)d_ws;                        // 2 MB
  short* kw  = qw + (size_t)MROWS * HD;             // 2 MB
  short* vtw = kw + (size_t)MROWS * HD;             // 2 MB
  short* wb  = vtw + (size_t)NB * HD * TSEQ;        // 384 KB

  wcvt<<<dim3(96), dim3(256), 0, stream>>>(Wq, Wk, Wv, wb);
  qkv_proj<<<dim3(MROWS / 32), dim3(256), 0, stream>>>(x, wb, qw, kw, vtw);
  attn<<<dim3(512), dim3(256), 0, stream>>>(qw, kw, vtw, out);
}